// Round 3
// baseline (4220.891 us; speedup 1.0000x reference)
//
#include <hip/hip_runtime.h>
#include <hip/hip_bf16.h>

// GCN 2-layer fused:  out = A·A·(x @ (W1@W2)) + (A·1)⊗(b1@W2) + b2
// A = D^-1/2 (Adj + I) D^-1/2,  applied as edge-list scatter with fp32 atomics.
// Runtime-detects float dtype (f32 vs bf16) and edge dtype (int32 vs int64).

typedef __attribute__((ext_vector_type(8))) short short8;   // 8 bf16 (4 VGPRs)
typedef __attribute__((ext_vector_type(4))) float f32x4;

#define DIN 512
#define DOUT 128

__device__ inline short f2bs(float f) {
    __hip_bfloat16 h = __float2bfloat16(f);
    return __builtin_bit_cast(short, h);
}
__device__ inline float b2f(const void* p, long long idx) {
    return __bfloat162float(((const __hip_bfloat16*)p)[idx]);
}

// ---- float dtype detect on x: bf16 data -> ~100% of uint16s have N(0,1)-plausible
//      exponents; f32 data -> low-mantissa halves are uniform -> ~56%.  fflag=1 => bf16.
__global__ void k_fdetect(const unsigned short* __restrict__ xr, int* __restrict__ fflag) {
    __shared__ int cnt;
    if (threadIdx.x == 0) cnt = 0;
    __syncthreads();
    int local = 0;
    for (int i = threadIdx.x; i < 8192; i += 256) {
        unsigned e = (xr[i] >> 7) & 0xFF;
        if (e == 0 || (e >= 0x70 && e <= 0x8E)) local++;
    }
    atomicAdd(&cnt, local);
    __syncthreads();
    if (threadIdx.x == 0) *fflag = (cnt >= 7373) ? 1 : 0;   // >=90% plausible => bf16
}

// ---- edge dtype detect: odd int32 words of int64 node ids are all zero.  eflag=1 => int32.
__global__ void k_edetect(const int* __restrict__ ei_raw, int* __restrict__ eflag) {
    __shared__ int any;
    if (threadIdx.x == 0) any = 0;
    __syncthreads();
    for (int i = threadIdx.x; i < 4096; i += 256)
        if (ei_raw[2 * i + 1] != 0) any = 1;   // benign race
    __syncthreads();
    if (threadIdx.x == 0) *eflag = any;
}

__global__ __launch_bounds__(256) void k_convert(const void* __restrict__ ei_raw,
                                                 const int* __restrict__ eflag,
                                                 int* __restrict__ ei32, int total) {
    int t = blockIdx.x * 256 + threadIdx.x;
    if (t >= total) return;
    if (*eflag) ei32[t] = ((const int*)ei_raw)[t];
    else        ei32[t] = (int)((const long long*)ei_raw)[t];
}

// ---- W12T[j][i] = sum_c W1[i,c] * W2[c,j]  (bf16, stored transposed [128][512])
__global__ __launch_bounds__(256) void k_w12(const void* __restrict__ W1,
                                             const void* __restrict__ W2,
                                             const int* __restrict__ fflag,
                                             __hip_bfloat16* __restrict__ w12t) {
    int t = blockIdx.x * 256 + threadIdx.x;      // [0, 512*128)
    int d = t >> 7, j = t & 127;
    float acc = 0.f;
    if (*fflag) {
        for (int c = 0; c < 512; ++c)
            acc += b2f(W1, d * 512 + c) * b2f(W2, c * 128 + j);
    } else {
        const float* w1 = (const float*)W1;
        const float* w2 = (const float*)W2;
        for (int c = 0; c < 512; ++c)
            acc += w1[d * 512 + c] * w2[c * 128 + j];
    }
    w12t[j * 512 + d] = __float2bfloat16(acc);
}

// ---- b12[j] = sum_c b1[c] * W2[c,j]  (fp32)
__global__ void k_b12(const void* __restrict__ b1, const void* __restrict__ W2,
                      const int* __restrict__ fflag, float* __restrict__ b12) {
    int j = threadIdx.x;                         // 128 threads
    float acc = 0.f;
    if (*fflag) {
        for (int c = 0; c < 512; ++c)
            acc += b2f(b1, c) * b2f(W2, c * 128 + j);
    } else {
        const float* bb = (const float*)b1;
        const float* w2 = (const float*)W2;
        for (int c = 0; c < 512; ++c)
            acc += bb[c] * w2[c * 128 + j];
    }
    b12[j] = acc;
}

// ---- degree over dst (real edges only; +1 self-loop added in k_dinv)
__global__ __launch_bounds__(256) void k_deg(const int* __restrict__ ei, int E,
                                             int* __restrict__ degi) {
    int e = blockIdx.x * 256 + threadIdx.x;
    if (e >= E) return;
    atomicAdd(&degi[ei[E + e]], 1);
}

__global__ __launch_bounds__(256) void k_dinv(const int* __restrict__ degi,
                                              float* __restrict__ dinv, int n) {
    int i = blockIdx.x * 256 + threadIdx.x;
    if (i >= n) return;
    dinv[i] = rsqrtf((float)(degi[i] + 1));      // +1: self-loop
}

// ---- rowsum[d] = sum over real edges (s->d) of dinv[s]
__global__ __launch_bounds__(256) void k_rowsum(const int* __restrict__ ei, int E,
                                                const float* __restrict__ dinv,
                                                float* __restrict__ rowsum) {
    int e = blockIdx.x * 256 + threadIdx.x;
    if (e >= E) return;
    unsafeAtomicAdd(&rowsum[ei[E + e]], dinv[ei[e]]);
}

// ---- M = x @ W12   (bf16 MFMA, fp32 out).  One wave: 32 rows x 128 cols.
__global__ __launch_bounds__(256) void k_gemm(const void* __restrict__ xv,
                                              const __hip_bfloat16* __restrict__ w12t,
                                              const int* __restrict__ fflag,
                                              float* __restrict__ M, int n) {
    int wave = (blockIdx.x * 256 + threadIdx.x) >> 6;
    int lane = threadIdx.x & 63;
    int row0 = wave * 32;
    if (row0 >= n) return;
    int quad = lane >> 4, m16 = lane & 15;
    const short* ws = (const short*)w12t;

    f32x4 acc[2][8];
#pragma unroll
    for (int i = 0; i < 2; ++i)
#pragma unroll
        for (int j = 0; j < 8; ++j) acc[i][j] = (f32x4){0.f, 0.f, 0.f, 0.f};

    int ra = row0 + m16, rb = row0 + 16 + m16;
    if (ra >= n) ra = n - 1;                     // tail-safe (reads only)
    if (rb >= n) rb = n - 1;

    if (*fflag) {            // ---- bf16 input path
        const short* xs = (const short*)xv;
#pragma unroll 2
        for (int ks = 0; ks < 16; ++ks) {
            int k0 = ks * 32 + quad * 8;
            short8 A0 = *(const short8*)(xs + (size_t)ra * 512 + k0);  // A[m=lane&15][k=quad*8+j]
            short8 A1 = *(const short8*)(xs + (size_t)rb * 512 + k0);
#pragma unroll
            for (int nc = 0; nc < 8; ++nc) {
                short8 B = *(const short8*)(ws + (nc * 16 + m16) * 512 + k0);
                acc[0][nc] = __builtin_amdgcn_mfma_f32_16x16x32_bf16(A0, B, acc[0][nc], 0, 0, 0);
                acc[1][nc] = __builtin_amdgcn_mfma_f32_16x16x32_bf16(A1, B, acc[1][nc], 0, 0, 0);
            }
        }
    } else {                 // ---- f32 input path: load f32, cvt to bf16 fragments
        const float* xf = (const float*)xv;
#pragma unroll 2
        for (int ks = 0; ks < 16; ++ks) {
            int k0 = ks * 32 + quad * 8;
            float4 u0 = *(const float4*)(xf + (size_t)ra * 512 + k0);
            float4 u1 = *(const float4*)(xf + (size_t)ra * 512 + k0 + 4);
            float4 v0 = *(const float4*)(xf + (size_t)rb * 512 + k0);
            float4 v1 = *(const float4*)(xf + (size_t)rb * 512 + k0 + 4);
            short8 A0, A1;
            A0[0] = f2bs(u0.x); A0[1] = f2bs(u0.y); A0[2] = f2bs(u0.z); A0[3] = f2bs(u0.w);
            A0[4] = f2bs(u1.x); A0[5] = f2bs(u1.y); A0[6] = f2bs(u1.z); A0[7] = f2bs(u1.w);
            A1[0] = f2bs(v0.x); A1[1] = f2bs(v0.y); A1[2] = f2bs(v0.z); A1[3] = f2bs(v0.w);
            A1[4] = f2bs(v1.x); A1[5] = f2bs(v1.y); A1[6] = f2bs(v1.z); A1[7] = f2bs(v1.w);
#pragma unroll
            for (int nc = 0; nc < 8; ++nc) {
                short8 B = *(const short8*)(ws + (nc * 16 + m16) * 512 + k0);
                acc[0][nc] = __builtin_amdgcn_mfma_f32_16x16x32_bf16(A0, B, acc[0][nc], 0, 0, 0);
                acc[1][nc] = __builtin_amdgcn_mfma_f32_16x16x32_bf16(A1, B, acc[1][nc], 0, 0, 0);
            }
        }
    }
    // C/D: col = lane&15, row = quad*4 + reg
#pragma unroll
    for (int rt = 0; rt < 2; ++rt)
#pragma unroll
        for (int nc = 0; nc < 8; ++nc)
#pragma unroll
            for (int r = 0; r < 4; ++r) {
                int row = row0 + rt * 16 + quad * 4 + r;
                if (row < n)
                    M[(size_t)row * 128 + nc * 16 + m16] = acc[rt][nc][r];
            }
}

// ---- edge aggregation: dst_acc[d,:] += dinv[s]*dinv[d] * src_feat[s,:]
//      e in [0,E): real edges;  e in [E,E+n): self-loops.  32 thr/edge, float4/thr.
__global__ __launch_bounds__(256) void k_agg(const int* __restrict__ ei, int E, int n,
                                             const float* __restrict__ dinv,
                                             const float* __restrict__ src_feat,
                                             float* __restrict__ dst_acc) {
    int t = blockIdx.x * 256 + threadIdx.x;
    int e = t >> 5;
    if (e >= E + n) return;
    int c = (t & 31) * 4;
    int s, d; float w;
    if (e < E) {
        s = ei[e]; d = ei[E + e];
        w = dinv[s] * dinv[d];
    } else {
        s = d = e - E;
        w = dinv[s] * dinv[s];
    }
    const float4 v = *(const float4*)(src_feat + (size_t)s * 128 + c);
    float* p = dst_acc + (size_t)d * 128 + c;
    unsafeAtomicAdd(p + 0, w * v.x);
    unsafeAtomicAdd(p + 1, w * v.y);
    unsafeAtomicAdd(p + 2, w * v.z);
    unsafeAtomicAdd(p + 3, w * v.w);
}

// ---- out = B2 + dinv_i*(rowsum_i + dinv_i) * b12[c] + b2[c]   (store per dtype flag)
__global__ __launch_bounds__(256) void k_final(const float* __restrict__ B2,
                                               const float* __restrict__ rowsum,
                                               const float* __restrict__ dinv,
                                               const float* __restrict__ b12,
                                               const void* __restrict__ b2,
                                               const int* __restrict__ fflag,
                                               void* __restrict__ out, int n) {
    int t = blockIdx.x * 256 + threadIdx.x;
    if (t >= n * 128) return;
    int i = t >> 7, c = t & 127;
    float coef = dinv[i] * (rowsum[i] + dinv[i]);
    if (*fflag) {
        float v = B2[t] + coef * b12[c] + b2f(b2, c);
        ((__hip_bfloat16*)out)[t] = __float2bfloat16(v);
    } else {
        float v = B2[t] + coef * b12[c] + ((const float*)b2)[c];
        ((float*)out)[t] = v;
    }
}

// ---- diagnostic: workspace too small -> fill out with recognizable sentinel
__global__ __launch_bounds__(256) void k_sentinel(unsigned short* __restrict__ out, int total) {
    int t = blockIdx.x * 256 + threadIdx.x;
    if (t < total) out[t] = 0x4641;              // bf16(12344)
}

extern "C" void kernel_launch(void* const* d_in, const int* in_sizes, int n_in,
                              void* d_out, int out_size, void* d_ws, size_t ws_size,
                              hipStream_t stream) {
    const int n = out_size / DOUT;               // 100000

    // ---- identify inputs by unique flat element counts; positional fallback.
    const void *x = nullptr, *W1 = nullptr, *b1 = nullptr, *W2 = nullptr, *b2 = nullptr;
    const void* ei_raw = nullptr;
    int E = 0;
    const long long nx = (long long)n * DIN;
    for (int i = 0; i < n_in; ++i) {
        long long s = in_sizes[i];
        if      (s == nx && !x)                      x  = d_in[i];
        else if (s == (long long)DIN * DIN && !W1)   W1 = d_in[i];
        else if (s == (long long)DIN && !b1)         b1 = d_in[i];
        else if (s == (long long)DIN * DOUT && !W2)  W2 = d_in[i];
        else if (s == (long long)DOUT && !b2)        b2 = d_in[i];
        else if (s == 1) { /* original_size scalar */ }
        else if (!ei_raw) { ei_raw = d_in[i]; E = (int)(s / 2); }
    }
    if (!x || !W1 || !b1 || !W2 || !b2 || !ei_raw) {   // fallback: documented order
        x  = d_in[0];
        ei_raw = d_in[1];  E = in_sizes[1] / 2;
        W1 = d_in[3]; b1 = d_in[4]; W2 = d_in[5]; b2 = d_in[6];
    }

    // ---- workspace layout
    char* ws = (char*)d_ws;
    size_t off = 0;
    auto alloc = [&](size_t bytes) { void* p = ws + off; off = (off + bytes + 255) & ~255ULL; return p; };
    int*   eflag  = (int*)alloc(4);
    int*   fflag  = (int*)alloc(4);
    int*   degi   = (int*)alloc((size_t)n * 4);
    float* dinv   = (float*)alloc((size_t)n * 4);
    float* rowsum = (float*)alloc((size_t)n * 4);
    float* b12    = (float*)alloc(DOUT * 4);
    __hip_bfloat16* w12t = (__hip_bfloat16*)alloc(DIN * DOUT * 2);
    int*   ei32   = (int*)alloc((size_t)2 * E * 4);
    float* M      = (float*)alloc((size_t)n * DOUT * 4);   // x@W12, reused as B2
    float* B1     = (float*)alloc((size_t)n * DOUT * 4);   // A·M

    if (ws_size < off) {   // workspace insufficient -> sentinel output, bail
        k_sentinel<<<(out_size + 255) / 256, 256, 0, stream>>>((unsigned short*)d_out, out_size);
        return;
    }

    hipMemsetAsync(degi, 0, (size_t)n * 4, stream);
    hipMemsetAsync(rowsum, 0, (size_t)n * 4, stream);
    hipMemsetAsync(B1, 0, (size_t)n * DOUT * 4, stream);

    // ---- dtype detection + edge normalization
    k_fdetect<<<1, 256, 0, stream>>>((const unsigned short*)x, fflag);
    k_edetect<<<1, 256, 0, stream>>>((const int*)ei_raw, eflag);
    k_convert<<<(2 * E + 255) / 256, 256, 0, stream>>>(ei_raw, eflag, ei32, 2 * E);

    k_w12<<<(DIN * DOUT) / 256, 256, 0, stream>>>(W1, W2, fflag, w12t);
    k_b12<<<1, 128, 0, stream>>>(b1, W2, fflag, b12);
    k_deg<<<(E + 255) / 256, 256, 0, stream>>>(ei32, E, degi);
    k_dinv<<<(n + 255) / 256, 256, 0, stream>>>(degi, dinv, n);
    k_rowsum<<<(E + 255) / 256, 256, 0, stream>>>(ei32, E, dinv, rowsum);

    int waves = (n + 31) / 32;
    k_gemm<<<(waves + 3) / 4, 256, 0, stream>>>(x, w12t, fflag, M, n);

    long long aggThreads = (long long)(E + n) * 32;
    k_agg<<<(int)((aggThreads + 255) / 256), 256, 0, stream>>>(ei32, E, n, dinv, M, B1);
    hipMemsetAsync(M, 0, (size_t)n * DOUT * 4, stream);
    k_agg<<<(int)((aggThreads + 255) / 256), 256, 0, stream>>>(ei32, E, n, dinv, B1, M);

    k_final<<<((n * DOUT) + 255) / 256, 256, 0, stream>>>(M, rowsum, dinv, b12, b2, fflag, d_out, n);
}

// Round 4
// 744.863 us; speedup vs baseline: 5.6667x; 5.6667x over previous
//
#include <hip/hip_runtime.h>
#include <hip/hip_bf16.h>

// GCN 2-layer fused:  out = A·A·(x @ (W1@W2)) + (A·1)⊗(b1@W2) + b2
// A = D^-1/2 (Adj + I) D^-1/2.  Aggregation is CSR gather (no fp32 atomics):
//   out[d] = dinv[d]*( sum_{s->d} dinv[s]*F[s] + dinv[d]*F[d] )
// Runtime-detects float dtype (f32 vs bf16) and edge dtype (int32 vs int64).

typedef __attribute__((ext_vector_type(8))) short short8;   // 8 bf16 (4 VGPRs)
typedef __attribute__((ext_vector_type(4))) float f32x4;

#define DIN 512
#define DOUT 128

__device__ inline short f2bs(float f) {
    __hip_bfloat16 h = __float2bfloat16(f);
    return __builtin_bit_cast(short, h);
}
__device__ inline float b2f(const void* p, long long idx) {
    return __bfloat162float(((const __hip_bfloat16*)p)[idx]);
}
__device__ inline int edge_at(const void* ei, int eflag, long long idx) {
    return eflag ? ((const int*)ei)[idx] : (int)((const long long*)ei)[idx];
}

// ---- float dtype detect on x: bf16 data -> ~100% of uint16s have N(0,1)-plausible
//      exponents; f32 data -> low-mantissa halves are uniform -> ~56%.  fflag=1 => bf16.
__global__ void k_fdetect(const unsigned short* __restrict__ xr, int* __restrict__ fflag) {
    __shared__ int cnt;
    if (threadIdx.x == 0) cnt = 0;
    __syncthreads();
    int local = 0;
    for (int i = threadIdx.x; i < 8192; i += 256) {
        unsigned e = (xr[i] >> 7) & 0xFF;
        if (e == 0 || (e >= 0x70 && e <= 0x8E)) local++;
    }
    atomicAdd(&cnt, local);
    __syncthreads();
    if (threadIdx.x == 0) *fflag = (cnt >= 7373) ? 1 : 0;   // >=90% plausible => bf16
}

// ---- edge dtype detect: odd int32 words of int64 node ids are all zero.  eflag=1 => int32.
__global__ void k_edetect(const int* __restrict__ ei_raw, int* __restrict__ eflag) {
    __shared__ int any;
    if (threadIdx.x == 0) any = 0;
    __syncthreads();
    for (int i = threadIdx.x; i < 4096; i += 256)
        if (ei_raw[2 * i + 1] != 0) any = 1;   // benign race
    __syncthreads();
    if (threadIdx.x == 0) *eflag = any;
}

// ---- W12T[j][i] = sum_c W1[i,c] * W2[c,j]  (bf16, stored transposed [128][512])
__global__ __launch_bounds__(256) void k_w12(const void* __restrict__ W1,
                                             const void* __restrict__ W2,
                                             const int* __restrict__ fflag,
                                             __hip_bfloat16* __restrict__ w12t) {
    int t = blockIdx.x * 256 + threadIdx.x;      // [0, 512*128)
    int d = t >> 7, j = t & 127;
    float acc = 0.f;
    if (*fflag) {
        for (int c = 0; c < 512; ++c)
            acc += b2f(W1, d * 512 + c) * b2f(W2, c * 128 + j);
    } else {
        const float* w1 = (const float*)W1;
        const float* w2 = (const float*)W2;
        for (int c = 0; c < 512; ++c)
            acc += w1[d * 512 + c] * w2[c * 128 + j];
    }
    w12t[j * 512 + d] = __float2bfloat16(acc);
}

// ---- b12[j] = sum_c b1[c] * W2[c,j]  (fp32)
__global__ void k_b12(const void* __restrict__ b1, const void* __restrict__ W2,
                      const int* __restrict__ fflag, float* __restrict__ b12) {
    int j = threadIdx.x;                         // 128 threads
    float acc = 0.f;
    if (*fflag) {
        for (int c = 0; c < 512; ++c)
            acc += b2f(b1, c) * b2f(W2, c * 128 + j);
    } else {
        const float* bb = (const float*)b1;
        const float* w2 = (const float*)W2;
        for (int c = 0; c < 512; ++c)
            acc += bb[c] * w2[c * 128 + j];
    }
    b12[j] = acc;
}

// ---- in-degree over dst (real edges; self-loop added analytically)
__global__ __launch_bounds__(256) void k_deg(const void* __restrict__ ei,
                                             const int* __restrict__ eflag, int E,
                                             int* __restrict__ degi) {
    int e = blockIdx.x * 256 + threadIdx.x;
    if (e >= E) return;
    atomicAdd(&degi[edge_at(ei, *eflag, (long long)E + e)], 1);
}

__global__ __launch_bounds__(256) void k_dinv(const int* __restrict__ degi,
                                              float* __restrict__ dinv, int n) {
    int i = blockIdx.x * 256 + threadIdx.x;
    if (i >= n) return;
    dinv[i] = rsqrtf((float)(degi[i] + 1));      // +1: self-loop
}

// ---- exclusive scan over degi -> row_ptr (3-kernel two-level scan)
__global__ __launch_bounds__(256) void k_scan1(const int* __restrict__ degi,
                                               int* __restrict__ row_ptr,
                                               int* __restrict__ blocksum, int n) {
    __shared__ int sh[256];
    int t = threadIdx.x, g = blockIdx.x * 256 + t;
    int val = (g < n) ? degi[g] : 0;
    sh[t] = val;
    __syncthreads();
    for (int o = 1; o < 256; o <<= 1) {
        int v = (t >= o) ? sh[t - o] : 0;
        __syncthreads();
        if (t >= o) sh[t] += v;
        __syncthreads();
    }
    if (g < n) row_ptr[g] = sh[t] - val;         // exclusive within block
    if (t == 255) blocksum[blockIdx.x] = sh[255];
}

__global__ void k_scan2(int* __restrict__ blocksum, int nb) {
    __shared__ int sh[512];
    int t = threadIdx.x;
    int val = (t < nb) ? blocksum[t] : 0;
    sh[t] = val;
    __syncthreads();
    for (int o = 1; o < 512; o <<= 1) {
        int v = (t >= o) ? sh[t - o] : 0;
        __syncthreads();
        if (t >= o) sh[t] += v;
        __syncthreads();
    }
    if (t < nb) blocksum[t] = sh[t] - val;       // exclusive
}

__global__ __launch_bounds__(256) void k_scan3(int* __restrict__ row_ptr,
                                               int* __restrict__ cursor,
                                               const int* __restrict__ blocksum,
                                               int n, int E) {
    int g = blockIdx.x * 256 + threadIdx.x;
    if (g == 0) row_ptr[n] = E;
    if (g >= n) return;
    int v = row_ptr[g] + blocksum[blockIdx.x];
    row_ptr[g] = v;
    cursor[g] = v;
}

// ---- CSR fill: csr[pos] = (src, dinv[src]) bucketed by dst (order arbitrary)
__global__ __launch_bounds__(256) void k_fill(const void* __restrict__ ei,
                                              const int* __restrict__ eflag, int E,
                                              const float* __restrict__ dinv,
                                              int* __restrict__ cursor,
                                              int2* __restrict__ csr) {
    int e = blockIdx.x * 256 + threadIdx.x;
    if (e >= E) return;
    int f = *eflag;
    int s = edge_at(ei, f, e);
    int d = edge_at(ei, f, (long long)E + e);
    int pos = atomicAdd(&cursor[d], 1);
    csr[pos] = make_int2(s, __float_as_int(dinv[s]));
}

// ---- M = x @ W12   (bf16 MFMA, fp32 out).  One wave: 32 rows x 128 cols.
__global__ __launch_bounds__(256) void k_gemm(const void* __restrict__ xv,
                                              const __hip_bfloat16* __restrict__ w12t,
                                              const int* __restrict__ fflag,
                                              float* __restrict__ M, int n) {
    int wave = (blockIdx.x * 256 + threadIdx.x) >> 6;
    int lane = threadIdx.x & 63;
    int row0 = wave * 32;
    if (row0 >= n) return;
    int quad = lane >> 4, m16 = lane & 15;
    const short* ws = (const short*)w12t;

    f32x4 acc[2][8];
#pragma unroll
    for (int i = 0; i < 2; ++i)
#pragma unroll
        for (int j = 0; j < 8; ++j) acc[i][j] = (f32x4){0.f, 0.f, 0.f, 0.f};

    int ra = row0 + m16, rb = row0 + 16 + m16;
    if (ra >= n) ra = n - 1;                     // tail-safe (reads only)
    if (rb >= n) rb = n - 1;

    if (*fflag) {            // ---- bf16 input path
        const short* xs = (const short*)xv;
#pragma unroll 2
        for (int ks = 0; ks < 16; ++ks) {
            int k0 = ks * 32 + quad * 8;
            short8 A0 = *(const short8*)(xs + (size_t)ra * 512 + k0);  // A[m=lane&15][k=quad*8+j]
            short8 A1 = *(const short8*)(xs + (size_t)rb * 512 + k0);
#pragma unroll
            for (int nc = 0; nc < 8; ++nc) {
                short8 B = *(const short8*)(ws + (nc * 16 + m16) * 512 + k0);
                acc[0][nc] = __builtin_amdgcn_mfma_f32_16x16x32_bf16(A0, B, acc[0][nc], 0, 0, 0);
                acc[1][nc] = __builtin_amdgcn_mfma_f32_16x16x32_bf16(A1, B, acc[1][nc], 0, 0, 0);
            }
        }
    } else {                 // ---- f32 input path: load f32, cvt to bf16 fragments
        const float* xf = (const float*)xv;
#pragma unroll 2
        for (int ks = 0; ks < 16; ++ks) {
            int k0 = ks * 32 + quad * 8;
            float4 u0 = *(const float4*)(xf + (size_t)ra * 512 + k0);
            float4 u1 = *(const float4*)(xf + (size_t)ra * 512 + k0 + 4);
            float4 v0 = *(const float4*)(xf + (size_t)rb * 512 + k0);
            float4 v1 = *(const float4*)(xf + (size_t)rb * 512 + k0 + 4);
            short8 A0, A1;
            A0[0] = f2bs(u0.x); A0[1] = f2bs(u0.y); A0[2] = f2bs(u0.z); A0[3] = f2bs(u0.w);
            A0[4] = f2bs(u1.x); A0[5] = f2bs(u1.y); A0[6] = f2bs(u1.z); A0[7] = f2bs(u1.w);
            A1[0] = f2bs(v0.x); A1[1] = f2bs(v0.y); A1[2] = f2bs(v0.z); A1[3] = f2bs(v0.w);
            A1[4] = f2bs(v1.x); A1[5] = f2bs(v1.y); A1[6] = f2bs(v1.z); A1[7] = f2bs(v1.w);
#pragma unroll
            for (int nc = 0; nc < 8; ++nc) {
                short8 B = *(const short8*)(ws + (nc * 16 + m16) * 512 + k0);
                acc[0][nc] = __builtin_amdgcn_mfma_f32_16x16x32_bf16(A0, B, acc[0][nc], 0, 0, 0);
                acc[1][nc] = __builtin_amdgcn_mfma_f32_16x16x32_bf16(A1, B, acc[1][nc], 0, 0, 0);
            }
        }
    }
    // C/D: col = lane&15, row = quad*4 + reg
#pragma unroll
    for (int rt = 0; rt < 2; ++rt)
#pragma unroll
        for (int nc = 0; nc < 8; ++nc)
#pragma unroll
            for (int r = 0; r < 4; ++r) {
                int row = row0 + rt * 16 + quad * 4 + r;
                if (row < n)
                    M[(size_t)row * 128 + nc * 16 + m16] = acc[rt][nc][r];
            }
}

// ---- CSR gather: one wave per node, float2 per lane (128 features).
//      FINAL=false: dstf[d] = dinv[d]*(sum + dinv[d]*src[d])
//      FINAL=true : fused epilogue  out = acc + dinv[d]*(wsum+dinv[d])*b12 + b2
template <bool FINAL>
__global__ __launch_bounds__(256) void k_gather(const int* __restrict__ row_ptr,
                                                const int2* __restrict__ csr,
                                                const float* __restrict__ dinv,
                                                const float* __restrict__ src_feat,
                                                float* __restrict__ dstf,
                                                const float* __restrict__ b12,
                                                const void* __restrict__ b2,
                                                const int* __restrict__ fflag,
                                                void* __restrict__ out, int n) {
    int d = blockIdx.x * 4 + (threadIdx.x >> 6);
    if (d >= n) return;
    int lane = threadIdx.x & 63;
    int c = lane * 2;
    float di = dinv[d];
    float2 self = *(const float2*)(src_feat + (size_t)d * 128 + c);
    float ax = di * self.x, ay = di * self.y;
    float wsum = 0.f;
    int beg = row_ptr[d], end = row_ptr[d + 1];
    for (int e = beg; e < end; ++e) {
        int2 rec = csr[e];                       // wave-uniform broadcast load
        float w = __int_as_float(rec.y);
        float2 v = *(const float2*)(src_feat + (size_t)rec.x * 128 + c);
        ax += w * v.x;
        ay += w * v.y;
        wsum += w;
    }
    ax *= di;
    ay *= di;
    if (!FINAL) {
        *(float2*)(dstf + (size_t)d * 128 + c) = make_float2(ax, ay);
    } else {
        float coef = di * (wsum + di);
        if (*fflag) {
            unsigned short o0 = (unsigned short)f2bs(ax + coef * b12[c]     + b2f(b2, c));
            unsigned short o1 = (unsigned short)f2bs(ay + coef * b12[c + 1] + b2f(b2, c + 1));
            *(ushort2*)((unsigned short*)out + (size_t)d * 128 + c) = make_ushort2(o0, o1);
        } else {
            float o0 = ax + coef * b12[c]     + ((const float*)b2)[c];
            float o1 = ay + coef * b12[c + 1] + ((const float*)b2)[c + 1];
            *(float2*)((float*)out + (size_t)d * 128 + c) = make_float2(o0, o1);
        }
    }
}

// ---- diagnostic: workspace too small -> fill out with recognizable sentinel
__global__ __launch_bounds__(256) void k_sentinel(unsigned short* __restrict__ out, int total) {
    int t = blockIdx.x * 256 + threadIdx.x;
    if (t < total) out[t] = 0x4641;              // bf16(12344)
}

extern "C" void kernel_launch(void* const* d_in, const int* in_sizes, int n_in,
                              void* d_out, int out_size, void* d_ws, size_t ws_size,
                              hipStream_t stream) {
    const int n = out_size / DOUT;               // 100000

    // ---- identify inputs by unique flat element counts; positional fallback.
    const void *x = nullptr, *W1 = nullptr, *b1 = nullptr, *W2 = nullptr, *b2 = nullptr;
    const void* ei_raw = nullptr;
    int E = 0;
    const long long nx = (long long)n * DIN;
    for (int i = 0; i < n_in; ++i) {
        long long s = in_sizes[i];
        if      (s == nx && !x)                      x  = d_in[i];
        else if (s == (long long)DIN * DIN && !W1)   W1 = d_in[i];
        else if (s == (long long)DIN && !b1)         b1 = d_in[i];
        else if (s == (long long)DIN * DOUT && !W2)  W2 = d_in[i];
        else if (s == (long long)DOUT && !b2)        b2 = d_in[i];
        else if (s == 1) { /* original_size scalar */ }
        else if (!ei_raw) { ei_raw = d_in[i]; E = (int)(s / 2); }
    }
    if (!x || !W1 || !b1 || !W2 || !b2 || !ei_raw) {   // fallback: documented order
        x  = d_in[0];
        ei_raw = d_in[1];  E = in_sizes[1] / 2;
        W1 = d_in[3]; b1 = d_in[4]; W2 = d_in[5]; b2 = d_in[6];
    }

    const int nb_scan = (n + 255) / 256;         // 391

    // ---- workspace layout
    char* ws = (char*)d_ws;
    size_t off = 0;
    auto alloc = [&](size_t bytes) { void* p = ws + off; off = (off + bytes + 255) & ~255ULL; return p; };
    int*   eflag    = (int*)alloc(4);
    int*   fflag    = (int*)alloc(4);
    int*   degi     = (int*)alloc((size_t)n * 4);
    float* dinv     = (float*)alloc((size_t)n * 4);
    float* b12      = (float*)alloc(DOUT * 4);
    __hip_bfloat16* w12t = (__hip_bfloat16*)alloc(DIN * DOUT * 2);
    int*   row_ptr  = (int*)alloc(((size_t)n + 1) * 4);
    int*   cursor   = (int*)alloc((size_t)n * 4);
    int*   blocksum = (int*)alloc(512 * 4);
    int2*  csr      = (int2*)alloc((size_t)E * 8);
    float* M        = (float*)alloc((size_t)n * DOUT * 4);   // x@W12
    float* B1       = (float*)alloc((size_t)n * DOUT * 4);   // A·M

    if (ws_size < off) {   // workspace insufficient -> sentinel output, bail
        k_sentinel<<<(out_size + 255) / 256, 256, 0, stream>>>((unsigned short*)d_out, out_size);
        return;
    }

    hipMemsetAsync(degi, 0, (size_t)n * 4, stream);

    // ---- dtype detection
    k_fdetect<<<1, 256, 0, stream>>>((const unsigned short*)x, fflag);
    k_edetect<<<1, 256, 0, stream>>>((const int*)ei_raw, eflag);

    // ---- weights
    k_w12<<<(DIN * DOUT) / 256, 256, 0, stream>>>(W1, W2, fflag, w12t);
    k_b12<<<1, 128, 0, stream>>>(b1, W2, fflag, b12);

    // ---- graph preprocessing: degree -> dinv -> CSR
    k_deg<<<(E + 255) / 256, 256, 0, stream>>>(ei_raw, eflag, E, degi);
    k_dinv<<<(n + 255) / 256, 256, 0, stream>>>(degi, dinv, n);
    k_scan1<<<nb_scan, 256, 0, stream>>>(degi, row_ptr, blocksum, n);
    k_scan2<<<1, 512, 0, stream>>>(blocksum, nb_scan);
    k_scan3<<<nb_scan, 256, 0, stream>>>(row_ptr, cursor, blocksum, n, E);
    k_fill<<<(E + 255) / 256, 256, 0, stream>>>(ei_raw, eflag, E, dinv, cursor, csr);

    // ---- GEMM: M = x @ W12
    int waves = (n + 31) / 32;
    k_gemm<<<(waves + 3) / 4, 256, 0, stream>>>(x, w12t, fflag, M, n);

    // ---- two CSR-gather aggregations (second one fuses bias epilogue + store)
    int nb_g = (n + 3) / 4;
    k_gather<false><<<nb_g, 256, 0, stream>>>(row_ptr, csr, dinv, M, B1,
                                              nullptr, nullptr, fflag, nullptr, n);
    k_gather<true><<<nb_g, 256, 0, stream>>>(row_ptr, csr, dinv, B1, nullptr,
                                             b12, b2, fflag, d_out, n);
}